// Round 14
// baseline (127.347 us; speedup 1.0000x reference)
//
#include <hip/hip_runtime.h>
#include <hip/hip_bf16.h>

// Problem constants (fixed by the reference):
constexpr int NB = 256;   // batch
constexpr int SQ = 512;   // sequence length
constexpr int ED = 512;   // encoder dim
constexpr int DD = 512;   // decoder dim
constexpr int UU = 64;    // attention units
constexpr int NT = 32;    // 16-row tiles per batch

typedef __attribute__((ext_vector_type(8))) short bf16x8;
typedef __attribute__((ext_vector_type(4))) float f32x4;

#define WAITVM(n) asm volatile("s_waitcnt vmcnt(" #n ")" ::: "memory")

__device__ __forceinline__ void stage16(const void* g, void* l) {
  __builtin_amdgcn_global_load_lds(
      (const __attribute__((address_space(1))) void*)g,
      (__attribute__((address_space(3))) void*)l, 16, 0, 0);
}

__device__ __forceinline__ unsigned short bf16_rne(float f) {
  unsigned int u = __float_as_uint(f);
  u += 0x7FFFu + ((u >> 16) & 1u);
  return (unsigned short)(u >> 16);
}

// Truncate-truncate pair split: v ~= hi + lo to ~2^-16 rel.
__device__ __forceinline__ uint2 split2(float v0, float v1) {
  unsigned int u0 = __float_as_uint(v0), u1 = __float_as_uint(v1);
  unsigned int h0 = u0 & 0xFFFF0000u, h1 = u1 & 0xFFFF0000u;
  unsigned int hi = (u0 >> 16) | h1;
  float r0 = v0 - __uint_as_float(h0);
  float r1 = v1 - __uint_as_float(h1);
  unsigned int lo = (__float_as_uint(r0) >> 16) | (__float_as_uint(r1) & 0xFFFF0000u);
  return make_uint2(hi, lo);
}

// ws layout (bytes):
//   [0,       65536)   : w2 bf16-hi MFMA B-fragments
//   [131072,  196608)  : dec[256][64]
//   [196608,  229376)  : lbuf[256][32]
//   [262144, 17039360) : ctile[256][32][512]
constexpr size_t WS_DEC   = 131072;
constexpr size_t WS_LBUF  = 196608;
constexpr size_t WS_CTILE = 262144;

// ---------------------------------------------------------------------------
// Kernel P: fused prep. Blocks 0..127: w2 -> bf16-hi B-fragments
// (layout: ks*2048 + nt*512 + lane*8 + j). Blocks 128..383: dec_proj.
// ---------------------------------------------------------------------------
__global__ __launch_bounds__(256) void prep_all(
    const float* __restrict__ w2, unsigned short* __restrict__ wsb,
    const float* __restrict__ dh, const float* __restrict__ w1,
    const float* __restrict__ w1b, const float* __restrict__ w2b,
    float* __restrict__ dec_ws) {
  const int blk = blockIdx.x;
  __shared__ float red[256];
  if (blk < 128) {
    int tid = blk * 256 + threadIdx.x;   // 0..32767
    int j    = tid & 7;
    int lane = (tid >> 3) & 63;
    int nt   = (tid >> 9) & 3;
    int ks   = tid >> 11;
    int e = ks * 32 + (lane >> 4) * 8 + j;
    int u = nt * 16 + (lane & 15);
    wsb[tid] = bf16_rne(w2[e * UU + u]);
  } else {
    const int b = blk - 128;
    const int t = threadIdx.x;
    const int wave = t >> 6;
    const float* dhb = dh + (size_t)b * DD;
    const int e0 = wave * 128;
    float s = 0.f;
    #pragma unroll 8
    for (int i = 0; i < 128; ++i) {
      int e = e0 + i;
      s = fmaf(dhb[e], w1[e * UU + (t & 63)], s);
    }
    red[t] = s;
    __syncthreads();
    if (t < 64) {
      float d = w1b[t] + w2b[t] + red[t] + red[64 + t] + red[128 + t] + red[192 + t];
      dec_ws[b * UU + t] = d;
    }
  }
}

// ---------------------------------------------------------------------------
// Kernel A: ONE WAVE PER BLOCK (8192 blocks), one 16-row tile each.
// READ-X-ONCE (the round-14 hypothesis): the tile's 32 KB is DMA'd into an
// LDS slab a single time, and BOTH the projection k-loop AND the context
// pass consume it from LDS. All 13 prior rounds read x twice through the
// cache hierarchy (536 MB total); at a ~5 TB/s-class cached-read path that
// alone is ~100 us — matching the invariant dur across every structure.
//  - slab source-XOR-swizzled per row (^((row&7)<<4), round-12-verified) so
//    both proj fragment reads and context row reads are <=4-way conflicts.
//  - zero barriers; single WAITVM(0) after the 32 staging DMAs.
//  - B-hi streamed from L2 with plain loads (compiler waitcnts undercount
//    the DMA FIFO at worst -> wait longer -> safe).
//  - softmax uses the CONSTANT shift M = sum_u |v_u| (scores are tanh-
//    bounded) -> no per-tile max, no mbuf; combine = one uniform 1/L scale.
// 32 KB LDS/block -> 5 independent self-paced waves per CU.
// ---------------------------------------------------------------------------
__global__ __launch_bounds__(64) void attn_wave(
    const float* __restrict__ x,
    const float* __restrict__ vk,
    const unsigned short* __restrict__ wsb,
    const float* __restrict__ dec_ws,
    float* __restrict__ lbuf,
    float* __restrict__ ctile,
    float* __restrict__ out)
{
  const int bid = blockIdx.x;
  const int b  = bid >> 5;
  const int tl = bid & 31;
  const int lane = threadIdx.x;        // 0..63
  const int ul = lane & 15;            // row within tile / col sel
  const int g  = lane >> 4;            // k-subgroup 0..3
  const int swz = (ul & 7) << 4;

  __shared__ __align__(16) unsigned char slab[32768];  // 16 rows x 2 KB

  const char* gsrc = (const char*)x + (size_t)(b * SQ + tl * 16) * 2048;

  // ---- stage the whole tile once (32 DMAs, source pre-swizzled per row) ---
  #pragma unroll
  for (int r = 0; r < 16; ++r) {
    #pragma unroll
    for (int h = 0; h < 2; ++h) {
      int off = h * 1024 + lane * 16;
      stage16(gsrc + (size_t)r * 2048 + (size_t)(off ^ ((r & 7) << 4)),
              &slab[r * 2048 + off]);
    }
  }

  // ---- scalar-side prologue loads (compiler-managed waits) ----------------
  float dv[4], vv[4];
  #pragma unroll
  for (int n = 0; n < 4; ++n) {
    dv[n] = dec_ws[b * UU + n * 16 + ul];
    vv[n] = vk[n * 16 + ul];
  }
  float av = fabsf(vk[lane]);
  av += __shfl_xor(av, 1);
  av += __shfl_xor(av, 2);
  av += __shfl_xor(av, 4);
  av += __shfl_xor(av, 8);
  av += __shfl_xor(av, 16);
  av += __shfl_xor(av, 32);
  const float M = av;                  // exact bound: |score| <= sum|v|

  WAITVM(0);                           // slab resident (own-wave DMAs only)

  // ---- projection k-loop: A from slab (LDS), B from L2 --------------------
  const f32x4 zero4 = {0.f, 0.f, 0.f, 0.f};
  f32x4 acc[4];
  #pragma unroll
  for (int n = 0; n < 4; ++n) acc[n] = zero4;

  const unsigned short* bp = wsb + lane * 8;
  const unsigned char* Ab = &slab[ul * 2048];

  #pragma unroll
  for (int k = 0; k < 16; ++k) {
    bf16x8 bhi[4];
    #pragma unroll
    for (int n = 0; n < 4; ++n)
      bhi[n] = *(const bf16x8*)(bp + k * 2048 + n * 512);
    f32x4 a0 = *(const f32x4*)(Ab + ((g * 32 + k * 128) ^ swz));
    f32x4 a1 = *(const f32x4*)(Ab + ((g * 32 + k * 128 + 16) ^ swz));
    uint2 p0 = split2(a0[0], a0[1]);
    uint2 p1 = split2(a0[2], a0[3]);
    uint2 p2 = split2(a1[0], a1[1]);
    uint2 p3 = split2(a1[2], a1[3]);
    unsigned int hiw[4] = {p0.x, p1.x, p2.x, p3.x};
    unsigned int low[4] = {p0.y, p1.y, p2.y, p3.y};
    bf16x8 ahi, alo;
    memcpy(&ahi, hiw, 16);
    memcpy(&alo, low, 16);
    #pragma unroll
    for (int n = 0; n < 4; ++n) {
      acc[n] = __builtin_amdgcn_mfma_f32_16x16x32_bf16(ahi, bhi[n], acc[n], 0, 0, 0);
      acc[n] = __builtin_amdgcn_mfma_f32_16x16x32_bf16(alo, bhi[n], acc[n], 0, 0, 0);
    }
  }

  // ---- scores + bounded-shift softmax (shuffles only) ---------------------
  // C/D layout (m89/m91): row = g*4 + r, col u = n*16 + ul
  float psc[4];
  #pragma unroll
  for (int r = 0; r < 4; ++r) {
    float s = 0.f;
    #pragma unroll
    for (int n = 0; n < 4; ++n) {
      float z = acc[n][r] + dv[n];
      float ez = __expf(2.f * z);              // tanh via exp
      float th = 1.f - 2.f / (ez + 1.f);
      s = fmaf(th, vv[n], s);
    }
    s += __shfl_xor(s, 1);
    s += __shfl_xor(s, 2);
    s += __shfl_xor(s, 4);
    s += __shfl_xor(s, 8);     // all 16 lanes of the row group hold it
    psc[r] = s;
  }
  float p[4];
  float lsum = 0.f;
  #pragma unroll
  for (int r = 0; r < 4; ++r) { p[r] = __expf(psc[r] - M); lsum += p[r]; }
  lsum += __shfl_xor(lsum, 16);
  lsum += __shfl_xor(lsum, 32);      // tile exp-sum, all lanes

  if (ul == 0) {
    float* att = out + (size_t)NB * ED + (size_t)b * SQ + tl * 16;
    #pragma unroll
    for (int r = 0; r < 4; ++r) att[g * 4 + r] = p[r];   // unnormalized
  }
  if (lane == 0) lbuf[b * NT + tl] = lsum;

  // ---- context from the SAME slab (no second global read of x) -----------
  {
    f32x4 c0 = zero4, c1 = zero4;
    #pragma unroll
    for (int rr = 0; rr < 16; ++rr) {
      const unsigned char* Rb = &slab[rr * 2048];
      const int sw2 = (rr & 7) << 4;
      f32x4 v0 = *(const f32x4*)(Rb + ((lane * 32) ^ sw2));
      f32x4 v1 = *(const f32x4*)(Rb + ((lane * 32 + 16) ^ sw2));
      float pi = __shfl(p[rr & 3], (rr >> 2) << 4);
      c0[0] = fmaf(pi, v0[0], c0[0]);
      c0[1] = fmaf(pi, v0[1], c0[1]);
      c0[2] = fmaf(pi, v0[2], c0[2]);
      c0[3] = fmaf(pi, v0[3], c0[3]);
      c1[0] = fmaf(pi, v1[0], c1[0]);
      c1[1] = fmaf(pi, v1[1], c1[1]);
      c1[2] = fmaf(pi, v1[2], c1[2]);
      c1[3] = fmaf(pi, v1[3], c1[3]);
    }
    float* ct = ctile + ((size_t)b * NT + tl) * ED + lane * 8;
    *(f32x4*)ct = c0;
    *(f32x4*)(ct + 4) = c1;
  }
}

// ---------------------------------------------------------------------------
// Kernel B: combine. All tiles share the shift M, so L = sum of tile sums;
// att *= 1/L in place; ctx = (sum_t ctile_t) / L.
// ---------------------------------------------------------------------------
__global__ __launch_bounds__(256) void combine(
    const float* __restrict__ lbuf,
    const float* __restrict__ ctile, float* __restrict__ out) {
  const int b = blockIdx.x;
  const int t = threadIdx.x;

  float L = 0.f;
  #pragma unroll 8
  for (int j = 0; j < NT; ++j) L += lbuf[b * NT + j];
  const float inv = 1.f / L;

  float* att = out + (size_t)NB * ED + (size_t)b * SQ;
  #pragma unroll
  for (int s = t; s < SQ; s += 256) att[s] *= inv;

  const float* ct = ctile + (size_t)b * NT * ED;
  #pragma unroll
  for (int e = t; e < ED; e += 256) {
    float c = 0.f;
    #pragma unroll 8
    for (int j = 0; j < NT; ++j) c += ct[j * ED + e];
    out[(size_t)b * ED + e] = c * inv;
  }
}

// ---------------------------------------------------------------------------
extern "C" void kernel_launch(void* const* d_in, const int* in_sizes, int n_in,
                              void* d_out, int out_size, void* d_ws, size_t ws_size,
                              hipStream_t stream) {
  const float* dh  = (const float*)d_in[0];
  const float* x   = (const float*)d_in[1];
  const float* w1  = (const float*)d_in[2];
  const float* w1b = (const float*)d_in[3];
  const float* w2  = (const float*)d_in[4];
  const float* w2b = (const float*)d_in[5];
  const float* vk  = (const float*)d_in[6];
  // d_in[7] = v_bias: softmax exactly invariant -> unused.
  unsigned short* wsb = (unsigned short*)d_ws;
  float* dec_ws = (float*)((char*)d_ws + WS_DEC);
  float* lbuf   = (float*)((char*)d_ws + WS_LBUF);
  float* ctile  = (float*)((char*)d_ws + WS_CTILE);
  float* out = (float*)d_out;

  prep_all<<<384, 256, 0, stream>>>(w2, wsb, dh, w1, w1b, w2b, dec_ws);
  attn_wave<<<NB * NT, 64, 0, stream>>>(x, vk, wsb, dec_ws, lbuf, ctile, out);
  combine<<<NB, 256, 0, stream>>>(lbuf, ctile, out);
}

// Round 15
// 89.988 us; speedup vs baseline: 1.4152x; 1.4152x over previous
//
#include <hip/hip_runtime.h>
#include <hip/hip_bf16.h>

// Problem constants (fixed by the reference):
constexpr int NB = 256;   // batch
constexpr int SQ = 512;   // sequence length
constexpr int ED = 512;   // encoder dim
constexpr int DD = 512;   // decoder dim
constexpr int UU = 64;    // attention units
constexpr int NT = 32;    // 16-row tiles per batch

typedef __attribute__((ext_vector_type(8))) short bf16x8;
typedef __attribute__((ext_vector_type(4))) float f32x4;

#define WAITVM(n) asm volatile("s_waitcnt vmcnt(" #n ")" ::: "memory")

__device__ __forceinline__ void stage16(const void* g, void* l) {
  __builtin_amdgcn_global_load_lds(
      (const __attribute__((address_space(1))) void*)g,
      (__attribute__((address_space(3))) void*)l, 16, 0, 0);
}

__device__ __forceinline__ unsigned short bf16_rne(float f) {
  unsigned int u = __float_as_uint(f);
  u += 0x7FFFu + ((u >> 16) & 1u);
  return (unsigned short)(u >> 16);
}

// Truncate-truncate pair split: v ~= hi + lo to ~2^-16 rel.
__device__ __forceinline__ uint2 split2(float v0, float v1) {
  unsigned int u0 = __float_as_uint(v0), u1 = __float_as_uint(v1);
  unsigned int h0 = u0 & 0xFFFF0000u, h1 = u1 & 0xFFFF0000u;
  unsigned int hi = (u0 >> 16) | h1;
  float r0 = v0 - __uint_as_float(h0);
  float r1 = v1 - __uint_as_float(h1);
  unsigned int lo = (__float_as_uint(r0) >> 16) | (__float_as_uint(r1) & 0xFFFF0000u);
  return make_uint2(hi, lo);
}

// ws layout (bytes):
constexpr size_t WS_DEC   = 131072;
constexpr size_t WS_LBUF  = 196608;
constexpr size_t WS_CTILE = 262144;

// ---------------------------------------------------------------------------
// Kernel P: fused prep. Blocks 0..127: w2 -> bf16-hi B-fragments
// (layout: ks*2048 + nt*512 + lane*8 + j). Blocks 128..383: dec_proj.
// ---------------------------------------------------------------------------
__global__ __launch_bounds__(256) void prep_all(
    const float* __restrict__ w2, unsigned short* __restrict__ wsb,
    const float* __restrict__ dh, const float* __restrict__ w1,
    const float* __restrict__ w1b, const float* __restrict__ w2b,
    float* __restrict__ dec_ws) {
  const int blk = blockIdx.x;
  __shared__ float red[256];
  if (blk < 128) {
    int tid = blk * 256 + threadIdx.x;   // 0..32767
    int j    = tid & 7;
    int lane = (tid >> 3) & 63;
    int nt   = (tid >> 9) & 3;
    int ks   = tid >> 11;
    int e = ks * 32 + (lane >> 4) * 8 + j;
    int u = nt * 16 + (lane & 15);
    wsb[tid] = bf16_rne(w2[e * UU + u]);
  } else {
    const int b = blk - 128;
    const int t = threadIdx.x;
    const int wave = t >> 6;
    const float* dhb = dh + (size_t)b * DD;
    const int e0 = wave * 128;
    float s = 0.f;
    #pragma unroll 8
    for (int i = 0; i < 128; ++i) {
      int e = e0 + i;
      s = fmaf(dhb[e], w1[e * UU + (t & 63)], s);
    }
    red[t] = s;
    __syncthreads();
    if (t < 64) {
      float d = w1b[t] + w2b[t] + red[t] + red[64 + t] + red[128 + t] + red[192 + t];
      dec_ws[b * UU + t] = d;
    }
  }
}

// ---------------------------------------------------------------------------
// Kernel A: 8192 blocks, 256 threads = 4 waves, ONE 16-row tile per block.
// READ-ONCE + CONCURRENCY (r14 halved FETCH to 133 MB but collapsed to ~5
// waves/CU with bulk vmcnt(0) + 16-way-conflict context reads; this keeps
// the traffic win and fixes the execution):
//  - 32 KB slab staged once by all 4 waves (8 DMAs each; 32 KB/block in
//    flight during staging > 9.2 KB/CU HBM-saturation minimum).
//  - K-SPLIT proj: wave w does k-steps [w*4, w*4+4); partial acc reduced
//    through a conflict-free f32x4 LDS layout (one barrier).
//  - B-hi/dec/v prefetched to registers BEFORE the stage barrier.
//  - softmax: constant shift M = sum|v| (exact bound, r14-verified);
//    replicated per wave so context needs no p broadcast.
//  - context COLUMN-split: wave w owns cols [w*128,+128), lane reads 8 B
//    per row (max 4-way bank conflict vs r14's 16-way).
// 48.5 KB LDS -> 3 blocks/CU = 12 independent waves.
// ---------------------------------------------------------------------------
__global__ __launch_bounds__(256, 3) void attn_tile(
    const float* __restrict__ x,
    const float* __restrict__ vk,
    const unsigned short* __restrict__ wsb,
    const float* __restrict__ dec_ws,
    float* __restrict__ lbuf,
    float* __restrict__ ctile,
    float* __restrict__ out)
{
  const int bid = blockIdx.x;
  const int b  = bid >> 5;
  const int tl = bid & 31;
  const int t = threadIdx.x;
  const int wave = t >> 6;
  const int lane = t & 63;
  const int ul = lane & 15;            // A row select / col sel
  const int g  = lane >> 4;            // k-subgroup 0..3
  const int swz = (ul & 7) << 4;

  __shared__ __align__(16) unsigned char slab[16][2048];  // 32 KB
  __shared__ __align__(16) f32x4 red[4 * 4 * 64];         // 16 KB, [w][n][lane]

  const char* gsrc = (const char*)x + (size_t)(b * SQ + tl * 16) * 2048;

  // ---- stage: wave w -> rows [w*4, w*4+4), source-XOR per row -------------
  #pragma unroll
  for (int r = 0; r < 4; ++r) {
    int row = wave * 4 + r;
    #pragma unroll
    for (int h = 0; h < 2; ++h) {
      int off = h * 1024 + lane * 16;
      stage16(gsrc + (size_t)row * 2048 + (size_t)(off ^ ((row & 7) << 4)),
              &slab[row][off]);
    }
  }

  // ---- register prefetch (L2) while DMAs fly ------------------------------
  const unsigned short* bp = wsb + lane * 8;
  bf16x8 bf[4][4];
  #pragma unroll
  for (int kk = 0; kk < 4; ++kk) {
    #pragma unroll
    for (int n = 0; n < 4; ++n)
      bf[kk][n] = *(const bf16x8*)(bp + (wave * 4 + kk) * 2048 + n * 512);
  }
  float dv[4], vv[4];
  #pragma unroll
  for (int n = 0; n < 4; ++n) {
    dv[n] = dec_ws[b * UU + n * 16 + ul];
    vv[n] = vk[n * 16 + ul];
  }
  float av = fabsf(vk[lane]);
  av += __shfl_xor(av, 1);
  av += __shfl_xor(av, 2);
  av += __shfl_xor(av, 4);
  av += __shfl_xor(av, 8);
  av += __shfl_xor(av, 16);
  av += __shfl_xor(av, 32);
  const float M = av;                  // exact bound: |score| <= sum|v|

  WAITVM(0);
  __syncthreads();                     // slab fully resident

  // ---- K-split projection: wave w covers k = w*4 .. w*4+4 -----------------
  const f32x4 zero4 = {0.f, 0.f, 0.f, 0.f};
  f32x4 acc[4];
  #pragma unroll
  for (int n = 0; n < 4; ++n) acc[n] = zero4;

  const unsigned char* Ab = &slab[ul][0];
  #pragma unroll
  for (int kk = 0; kk < 4; ++kk) {
    const int k = wave * 4 + kk;
    f32x4 a0 = *(const f32x4*)(Ab + ((g * 32 + k * 128) ^ swz));
    f32x4 a1 = *(const f32x4*)(Ab + ((g * 32 + k * 128 + 16) ^ swz));
    uint2 p0 = split2(a0[0], a0[1]);
    uint2 p1 = split2(a0[2], a0[3]);
    uint2 p2 = split2(a1[0], a1[1]);
    uint2 p3 = split2(a1[2], a1[3]);
    unsigned int hiw[4] = {p0.x, p1.x, p2.x, p3.x};
    unsigned int low[4] = {p0.y, p1.y, p2.y, p3.y};
    bf16x8 ahi, alo;
    memcpy(&ahi, hiw, 16);
    memcpy(&alo, low, 16);
    #pragma unroll
    for (int n = 0; n < 4; ++n) {
      acc[n] = __builtin_amdgcn_mfma_f32_16x16x32_bf16(ahi, bf[kk][n], acc[n], 0, 0, 0);
      acc[n] = __builtin_amdgcn_mfma_f32_16x16x32_bf16(alo, bf[kk][n], acc[n], 0, 0, 0);
    }
  }

  // ---- cross-wave acc reduce (conflict-free lane*16B layout) --------------
  #pragma unroll
  for (int n = 0; n < 4; ++n) red[(wave * 4 + n) * 64 + lane] = acc[n];
  __syncthreads();
  #pragma unroll
  for (int n = 0; n < 4; ++n) {
    f32x4 s0 = red[(0 * 4 + n) * 64 + lane];
    f32x4 s1 = red[(1 * 4 + n) * 64 + lane];
    f32x4 s2 = red[(2 * 4 + n) * 64 + lane];
    f32x4 s3 = red[(3 * 4 + n) * 64 + lane];
    acc[n][0] = s0[0] + s1[0] + s2[0] + s3[0];
    acc[n][1] = s0[1] + s1[1] + s2[1] + s3[1];
    acc[n][2] = s0[2] + s1[2] + s2[2] + s3[2];
    acc[n][3] = s0[3] + s1[3] + s2[3] + s3[3];
  }

  // ---- scores + bounded-shift softmax (replicated in every wave) ----------
  // C/D layout (m89/m91): row = g*4 + r, col u = n*16 + ul
  float psc[4];
  #pragma unroll
  for (int r = 0; r < 4; ++r) {
    float s = 0.f;
    #pragma unroll
    for (int n = 0; n < 4; ++n) {
      float z = acc[n][r] + dv[n];
      float ez = __expf(2.f * z);              // tanh via exp
      float th = 1.f - 2.f / (ez + 1.f);
      s = fmaf(th, vv[n], s);
    }
    s += __shfl_xor(s, 1);
    s += __shfl_xor(s, 2);
    s += __shfl_xor(s, 4);
    s += __shfl_xor(s, 8);     // all 16 lanes of the row group hold it
    psc[r] = s;
  }
  float p[4];
  float lsum = 0.f;
  #pragma unroll
  for (int r = 0; r < 4; ++r) { p[r] = __expf(psc[r] - M); lsum += p[r]; }
  lsum += __shfl_xor(lsum, 16);
  lsum += __shfl_xor(lsum, 32);      // tile exp-sum

  if (wave == 0 && ul == 0) {
    float* att = out + (size_t)NB * ED + (size_t)b * SQ + tl * 16;
    #pragma unroll
    for (int r = 0; r < 4; ++r) att[g * 4 + r] = p[r];   // unnormalized
  }
  if (t == 0) lbuf[b * NT + tl] = lsum;

  // ---- context from the SAME slab, column-split: wave w cols [w*128,+128) -
  {
    const int cbase = wave * 512 + lane * 8;   // byte offset within a row
    float cx = 0.f, cy = 0.f;
    #pragma unroll
    for (int rr = 0; rr < 16; ++rr) {
      const float2 v = *(const float2*)&slab[rr][cbase ^ ((rr & 7) << 4)];
      float pi = __shfl(p[rr & 3], (rr >> 2) << 4);
      cx = fmaf(pi, v.x, cx);
      cy = fmaf(pi, v.y, cy);
    }
    float* ct = ctile + ((size_t)b * NT + tl) * ED + wave * 128 + lane * 2;
    ct[0] = cx;
    ct[1] = cy;
  }
}

// ---------------------------------------------------------------------------
// Kernel B: combine. All tiles share the shift M, so L = sum of tile sums;
// att *= 1/L in place; ctx = (sum_t ctile_t) / L.
// ---------------------------------------------------------------------------
__global__ __launch_bounds__(256) void combine(
    const float* __restrict__ lbuf,
    const float* __restrict__ ctile, float* __restrict__ out) {
  const int b = blockIdx.x;
  const int t = threadIdx.x;

  float L = 0.f;
  #pragma unroll 8
  for (int j = 0; j < NT; ++j) L += lbuf[b * NT + j];
  const float inv = 1.f / L;

  float* att = out + (size_t)NB * ED + (size_t)b * SQ;
  #pragma unroll
  for (int s = t; s < SQ; s += 256) att[s] *= inv;

  const float* ct = ctile + (size_t)b * NT * ED;
  #pragma unroll
  for (int e = t; e < ED; e += 256) {
    float c = 0.f;
    #pragma unroll 8
    for (int j = 0; j < NT; ++j) c += ct[j * ED + e];
    out[(size_t)b * ED + e] = c * inv;
  }
}

// ---------------------------------------------------------------------------
extern "C" void kernel_launch(void* const* d_in, const int* in_sizes, int n_in,
                              void* d_out, int out_size, void* d_ws, size_t ws_size,
                              hipStream_t stream) {
  const float* dh  = (const float*)d_in[0];
  const float* x   = (const float*)d_in[1];
  const float* w1  = (const float*)d_in[2];
  const float* w1b = (const float*)d_in[3];
  const float* w2  = (const float*)d_in[4];
  const float* w2b = (const float*)d_in[5];
  const float* vk  = (const float*)d_in[6];
  // d_in[7] = v_bias: softmax exactly invariant -> unused.
  unsigned short* wsb = (unsigned short*)d_ws;
  float* dec_ws = (float*)((char*)d_ws + WS_DEC);
  float* lbuf   = (float*)((char*)d_ws + WS_LBUF);
  float* ctile  = (float*)((char*)d_ws + WS_CTILE);
  float* out = (float*)d_out;

  prep_all<<<384, 256, 0, stream>>>(w2, wsb, dh, w1, w1b, w2b, dec_ws);
  attn_tile<<<NB * NT, 256, 0, stream>>>(x, vk, wsb, dec_ws, lbuf, ctile, out);
  combine<<<NB, 256, 0, stream>>>(lbuf, ctile, out);
}